// Round 2
// baseline (10553.387 us; speedup 1.0000x reference)
//
#include <hip/hip_runtime.h>
#include <hip/hip_bf16.h>

typedef __attribute__((ext_vector_type(8))) short short8;
typedef __attribute__((ext_vector_type(4))) float f32x4;

__device__ __forceinline__ short f2b(float f) {
    unsigned u = __float_as_uint(f);
    unsigned r = (u + 0x7FFFu + ((u >> 16) & 1u)) >> 16;
    return (short)r;
}

// ---------------------------------------------------------------------------
// Embedding gather (f32): x0[n][p] = emb[tok[n]][p]
// ---------------------------------------------------------------------------
__global__ __launch_bounds__(256)
void k_embed(const int* __restrict__ tok, const float* __restrict__ emb,
             float* __restrict__ x0)
{
    int i = blockIdx.x * 256 + threadIdx.x;   // float4 index, 1024*128 total
    int n = i >> 7, p4 = i & 127;
    ((float4*)x0)[i] = ((const float4*)(emb + (size_t)tok[n] * 512))[p4];
}

// ---------------------------------------------------------------------------
// State init (f32 copies)
// ---------------------------------------------------------------------------
__global__ __launch_bounds__(256)
void k_state_init(const float* __restrict__ h0, const float* __restrict__ c0,
                  float* __restrict__ h, float* __restrict__ c, int n)
{
    int i = blockIdx.x * 256 + threadIdx.x;
    if (i < n) { h[i] = h0[i]; c[i] = c0[i]; }
}

// ---------------------------------------------------------------------------
// f32 -> bf16 bulk convert (for dec_W)
// ---------------------------------------------------------------------------
__global__ __launch_bounds__(256)
void k_f2b(const float* __restrict__ s, unsigned short* __restrict__ d, int n4)
{
    int i = blockIdx.x * 256 + threadIdx.x;
    if (i >= n4) return;
    float4 v = ((const float4*)s)[i];
    short4 o;
    o.x = f2b(v.x); o.y = f2b(v.y); o.z = f2b(v.z); o.w = f2b(v.w);
    ((short4*)d)[i] = o;
}

// ---------------------------------------------------------------------------
// MFMA bf16 GEMM: C[M,N] = A[M,K] * B[N,K]^T + bias
// Block 128x128, 4 waves (2x2), wave tile 64x64, K-step 32.
// BIN=0: A,B are f32 (converted to bf16 on LDS stage). BIN=1: A,B are bf16.
// EPI=0: C f32 row-major.  EPI=1: latent head -> bf16 with remap+tanh*gain.
// M%128==0, N%128==0, K%32==0.
// mfma_f32_16x16x32_bf16 layouts (verified, learn_hip m89/m91):
//   A: row=lane&15, k=(lane>>4)*8+i;  B: col=lane&15, k=(lane>>4)*8+i
//   C/D: col=lane&15, row=(lane>>4)*4+j
// ---------------------------------------------------------------------------
template <int EPI, int BIN>
__global__ __launch_bounds__(256)
void k_mfma_gemm(const void* __restrict__ Ap, const void* __restrict__ Bp,
                 const float* __restrict__ bias, void* __restrict__ Cp,
                 int M, int N, int K, const float* __restrict__ gain)
{
    __shared__ short As[128][40];   // 32 k + 8 pad (80B row stride)
    __shared__ short Bs[128][40];
    const int tid  = threadIdx.x;
    const int lane = tid & 63, wid = tid >> 6;
    const int wr = wid >> 1, wc = wid & 1;
    const int l15 = lane & 15, l4 = lane >> 4;
    const int row0 = blockIdx.y * 128, col0 = blockIdx.x * 128;
    const int srow = tid >> 1, skh = (tid & 1) << 4;

    f32x4 acc[4][4] = {};

    for (int k0 = 0; k0 < K; k0 += 32) {
        if (k0) __syncthreads();
        if (BIN == 0) {
            const float* A = (const float*)Ap;
            const float* B = (const float*)Bp;
            {
                const float4* sa = (const float4*)(A + (size_t)(row0 + srow) * K + k0 + skh);
                float tmp[16];
                *(float4*)&tmp[0]  = sa[0];
                *(float4*)&tmp[4]  = sa[1];
                *(float4*)&tmp[8]  = sa[2];
                *(float4*)&tmp[12] = sa[3];
                short8 v0, v1;
#pragma unroll
                for (int i = 0; i < 8; ++i) { v0[i] = f2b(tmp[i]); v1[i] = f2b(tmp[8 + i]); }
                *(short8*)&As[srow][skh]     = v0;
                *(short8*)&As[srow][skh + 8] = v1;
            }
            {
                const float4* sb = (const float4*)(B + (size_t)(col0 + srow) * K + k0 + skh);
                float tmp[16];
                *(float4*)&tmp[0]  = sb[0];
                *(float4*)&tmp[4]  = sb[1];
                *(float4*)&tmp[8]  = sb[2];
                *(float4*)&tmp[12] = sb[3];
                short8 v0, v1;
#pragma unroll
                for (int i = 0; i < 8; ++i) { v0[i] = f2b(tmp[i]); v1[i] = f2b(tmp[8 + i]); }
                *(short8*)&Bs[srow][skh]     = v0;
                *(short8*)&Bs[srow][skh + 8] = v1;
            }
        } else {
            const unsigned short* A = (const unsigned short*)Ap;
            const unsigned short* B = (const unsigned short*)Bp;
            const uint4* sa = (const uint4*)(A + (size_t)(row0 + srow) * K + k0 + skh);
            *(uint4*)&As[srow][skh]     = sa[0];
            *(uint4*)&As[srow][skh + 8] = sa[1];
            const uint4* sb = (const uint4*)(B + (size_t)(col0 + srow) * K + k0 + skh);
            *(uint4*)&Bs[srow][skh]     = sb[0];
            *(uint4*)&Bs[srow][skh + 8] = sb[1];
        }
        __syncthreads();

        short8 af[4], bfr[4];
#pragma unroll
        for (int i = 0; i < 4; ++i)
            af[i]  = *(const short8*)&As[wr * 64 + i * 16 + l15][l4 * 8];
#pragma unroll
        for (int i = 0; i < 4; ++i)
            bfr[i] = *(const short8*)&Bs[wc * 64 + i * 16 + l15][l4 * 8];
#pragma unroll
        for (int mi = 0; mi < 4; ++mi)
#pragma unroll
            for (int ni = 0; ni < 4; ++ni)
                acc[mi][ni] = __builtin_amdgcn_mfma_f32_16x16x32_bf16(
                    af[mi], bfr[ni], acc[mi][ni], 0, 0, 0);
    }

#pragma unroll
    for (int mi = 0; mi < 4; ++mi) {
#pragma unroll
        for (int ni = 0; ni < 4; ++ni) {
            int rb = row0 + wr * 64 + mi * 16 + l4 * 4;
            int cc = col0 + wc * 64 + ni * 16 + l15;
            float bv = bias[cc];
#pragma unroll
            for (int j = 0; j < 4; ++j) {
                float v = acc[mi][ni][j] + bv;
                if (EPI == 0) {
                    ((float*)Cp)[(size_t)(rb + j) * N + cc] = v;
                } else {
                    int e = cc >> 9, p = cc & 511;
                    ((unsigned short*)Cp)[(((size_t)(rb + j) * 8 + e) << 9) | p] =
                        (unsigned short)f2b(tanhf(v) * gain[p]);
                }
            }
        }
    }
}

// ---------------------------------------------------------------------------
// One LSTM time step, f32. Block 1024 threads = 16 batch x 16 units x 4 gates.
// Grid Dh/16. h staged in LDS in two K-halves.
// ---------------------------------------------------------------------------
__global__ __launch_bounds__(1024)
void k_lstm_step(const float* __restrict__ xg,     // (1024, 4*Dh)
                 const float* __restrict__ Whh,    // (4*Dh, Dh)
                 const float* __restrict__ h_in,   // (16, Dh)
                 float* __restrict__ h_out,        // (16, Dh)
                 float* __restrict__ c,            // (16, Dh) in/out
                 float* __restrict__ y,            // (1024, Dh)
                 int Dh, int t)
{
    __shared__ float hs[16][772];                  // K2<=768 f32, stride 772
    __shared__ float gs[4][16][16];                // [gate][b][ul]
    const int tid = threadIdx.x;
    const int b = tid & 15, ul = (tid >> 4) & 15, g = tid >> 8;
    const int u = blockIdx.x * 16 + ul;
    const int K2 = Dh >> 1, K24 = K2 >> 2;
    const float4* w = (const float4*)(Whh + ((size_t)g * Dh + u) * Dh);
    float a = 0.f;

    for (int half = 0; half < 2; ++half) {
        __syncthreads();
        for (int j = tid; j < (K24 << 4); j += 1024) {
            int r = j / K24, k = j - r * K24;
            ((float4*)hs[r])[k] =
                ((const float4*)(h_in + (size_t)r * Dh + (size_t)half * K2))[k];
        }
        __syncthreads();
        const float4* wh = w + half * K24;
        const float4* hrow = (const float4*)hs[b];
#pragma unroll 4
        for (int k = 0; k < K24; ++k) {
            float4 hv = hrow[k], wv = wh[k];
            a += hv.x * wv.x + hv.y * wv.y + hv.z * wv.z + hv.w * wv.w;
        }
    }
    gs[g][b][ul] = a;
    __syncthreads();

    if (g == 0) {
        const int n = t * 16 + b;
        const float* xr = xg + (size_t)n * 4 * Dh;
        float gi = xr[u]           + gs[0][b][ul];
        float gf = xr[Dh + u]      + gs[1][b][ul];
        float gg = xr[2 * Dh + u]  + gs[2][b][ul];
        float go = xr[3 * Dh + u]  + gs[3][b][ul];
        float si = 1.f / (1.f + expf(-gi));
        float sf = 1.f / (1.f + expf(-gf));
        float so = 1.f / (1.f + expf(-go));
        int ci = b * Dh + u;
        float cn = sf * c[ci] + si * tanhf(gg);
        c[ci] = cn;
        float hn = so * tanhf(cn);
        h_out[ci] = hn;
        y[(size_t)n * Dh + u] = hn;
    }
}

// ---------------------------------------------------------------------------
// Prior: softmax over 8 experts of out2(1024x1024) @ prior_W^T(8x1024)
// ---------------------------------------------------------------------------
__global__ __launch_bounds__(256)
void k_prior(const float* __restrict__ out2, const float* __restrict__ pW,
             float* __restrict__ prior)
{
    const int n = blockIdx.x;
    const int tid = threadIdx.x;
    const int e = tid >> 5, lane = tid & 31;
    const float* x = out2 + (size_t)n * 1024;
    const float* w = pW + (size_t)e * 1024;
    float s = 0.f;
    for (int k = lane; k < 1024; k += 32) s += x[k] * w[k];
#pragma unroll
    for (int o = 16; o; o >>= 1) s += __shfl_down(s, o, 32);
    __shared__ float es[8];
    if (lane == 0) es[e] = s;
    __syncthreads();
    if (tid == 0) {
        float m = -1e30f;
        for (int i = 0; i < 8; ++i) m = fmaxf(m, es[i]);
        float Z = 0.f, ex[8];
        for (int i = 0; i < 8; ++i) { ex[i] = expf(es[i] - m); Z += ex[i]; }
        for (int i = 0; i < 8; ++i) prior[(size_t)n * 8 + i] = ex[i] / Z;
    }
}

// ---------------------------------------------------------------------------
// Row stats over a logits chunk: per-row max and sum(exp(x-max)), 32000 cols.
// ---------------------------------------------------------------------------
__global__ __launch_bounds__(256)
void k_stats(const float* __restrict__ lg, float* __restrict__ stats)
{
    const int r = blockIdx.x;
    const float* row = lg + (size_t)r * 32000;
    const int tid = threadIdx.x;

    float m = -1e30f;
    for (int k = tid; k < 32000; k += 256) m = fmaxf(m, row[k]);
#pragma unroll
    for (int o = 32; o; o >>= 1) m = fmaxf(m, __shfl_down(m, o, 64));
    __shared__ float sm[4];
    if ((tid & 63) == 0) sm[tid >> 6] = m;
    __syncthreads();
    float M = fmaxf(fmaxf(sm[0], sm[1]), fmaxf(sm[2], sm[3]));

    float s = 0.f;
    for (int k = tid; k < 32000; k += 256) s += expf(row[k] - M);
#pragma unroll
    for (int o = 32; o; o >>= 1) s += __shfl_down(s, o, 64);
    __shared__ float ss[4];
    if ((tid & 63) == 0) ss[tid >> 6] = s;
    __syncthreads();
    if (tid == 0) {
        stats[2 * r]     = M;
        stats[2 * r + 1] = ss[0] + ss[1] + ss[2] + ss[3];
    }
}

// ---------------------------------------------------------------------------
// Combine: out[n][v] = log( sum_e prior[n,e]*exp(l[ne,v]-M_e)/Z_e + 1e-8 )
// ---------------------------------------------------------------------------
__global__ __launch_bounds__(256)
void k_combine(const float* __restrict__ lg, const float* __restrict__ stats,
               const float* __restrict__ prior, float* __restrict__ out, int n0)
{
    const int v = blockIdx.x * 256 + threadIdx.x;
    const int nl = blockIdx.y;
    const int n = n0 + nl;
    float acc = 0.f;
#pragma unroll
    for (int e = 0; e < 8; ++e) {
        int r = nl * 8 + e;
        float l = lg[(size_t)r * 32000 + v];
        acc += prior[(size_t)n * 8 + e] * expf(l - stats[2 * r]) / stats[2 * r + 1];
    }
    out[(size_t)n * 32000 + v] = logf(acc + 1e-8f);
}

// ---------------------------------------------------------------------------
extern "C" void kernel_launch(void* const* d_in, const int* in_sizes, int n_in,
                              void* d_out, int out_size, void* d_ws, size_t ws_size,
                              hipStream_t stream)
{
    const int*   tok  = (const int*)d_in[0];
    const float* h0   = (const float*)d_in[1];
    const float* c0   = (const float*)d_in[2];
    const float* h1   = (const float*)d_in[3];
    const float* c1   = (const float*)d_in[4];
    const float* h2   = (const float*)d_in[5];
    const float* c2   = (const float*)d_in[6];
    const float* emb  = (const float*)d_in[7];
    const float* Wih0 = (const float*)d_in[8];
    const float* Whh0 = (const float*)d_in[9];
    const float* b0   = (const float*)d_in[10];
    const float* Wih1 = (const float*)d_in[11];
    const float* Whh1 = (const float*)d_in[12];
    const float* b1   = (const float*)d_in[13];
    const float* Wih2 = (const float*)d_in[14];
    const float* Whh2 = (const float*)d_in[15];
    const float* b2   = (const float*)d_in[16];
    const float* priW = (const float*)d_in[17];
    const float* latW = (const float*)d_in[18];
    const float* latb = (const float*)d_in[19];
    const float* decW = (const float*)d_in[20];
    const float* decb = (const float*)d_in[21];
    const float* gain = (const float*)d_in[22];

    float* ws = (float*)d_ws;
    float* x0    = ws;                    // 1024*512
    float* x1    = x0 + 524288;           // 1024*1536
    float* x2    = x1 + 1572864;          // 1024*1536
    float* out2  = x2 + 1572864;          // 1024*1024
    float* xg    = out2 + 1048576;        // 1024*6144
    float* hA    = xg + 6291456;          // 16*1536 max
    float* hB    = hA + 24576;
    float* cb    = hB + 24576;
    float* pri   = cb + 24576;            // 1024*8
    float* stats = pri + 8192;            // 512*2
    unsigned short* latb16 = (unsigned short*)(stats + 1024);   // 8192*512 bf16
    unsigned short* decWb  = latb16 + 4194304;                  // 32000*512 bf16
    float* logits = (float*)(decWb + 16384000);                 // chunkRows*32000
    const size_t fixed_floats = 21382144ull;

    // embedding + decW conversion (independent, early)
    k_embed<<<512, 256, 0, stream>>>(tok, emb, x0);
    k_f2b<<<16000, 256, 0, stream>>>(decW, decWb, 4096000);

    // ---- layer 0 (512 -> 1536) ----
    k_state_init<<<96, 256, 0, stream>>>(h0, c0, hA, cb, 16 * 1536);
    k_mfma_gemm<0, 0><<<dim3(48, 8), 256, 0, stream>>>(
        x0, Wih0, b0, xg, 1024, 6144, 512, nullptr);
    for (int t = 0; t < 64; ++t) {
        const float* hin = (t & 1) ? hB : hA;
        float* hout = (t & 1) ? hA : hB;
        k_lstm_step<<<96, 1024, 0, stream>>>(xg, Whh0, hin, hout, cb, x1, 1536, t);
    }

    // ---- layer 1 (1536 -> 1536) ----
    k_state_init<<<96, 256, 0, stream>>>(h1, c1, hA, cb, 16 * 1536);
    k_mfma_gemm<0, 0><<<dim3(48, 8), 256, 0, stream>>>(
        x1, Wih1, b1, xg, 1024, 6144, 1536, nullptr);
    for (int t = 0; t < 64; ++t) {
        const float* hin = (t & 1) ? hB : hA;
        float* hout = (t & 1) ? hA : hB;
        k_lstm_step<<<96, 1024, 0, stream>>>(xg, Whh1, hin, hout, cb, x2, 1536, t);
    }

    // ---- layer 2 (1536 -> 1024) ----
    k_state_init<<<64, 256, 0, stream>>>(h2, c2, hA, cb, 16 * 1024);
    k_mfma_gemm<0, 0><<<dim3(32, 8), 256, 0, stream>>>(
        x2, Wih2, b2, xg, 1024, 4096, 1536, nullptr);
    for (int t = 0; t < 64; ++t) {
        const float* hin = (t & 1) ? hB : hA;
        float* hout = (t & 1) ? hA : hB;
        k_lstm_step<<<64, 1024, 0, stream>>>(xg, Whh2, hin, hout, cb, out2, 1024, t);
    }

    // ---- MoS head ----
    k_prior<<<1024, 256, 0, stream>>>(out2, priW, pri);
    k_mfma_gemm<1, 0><<<dim3(32, 8), 256, 0, stream>>>(
        out2, latW, latb, latb16, 1024, 4096, 1024, gain);

    // ---- decoder, chunked over rows of lat (8192 x 512 bf16) ----
    size_t ws_floats = ws_size / 4;
    int chunkRows = 512;
    while (chunkRows > 128 &&
           fixed_floats + (size_t)chunkRows * 32000 > ws_floats)
        chunkRows >>= 1;
    int nPer = chunkRows / 8;

    for (int nb = 0; nb < 1024; nb += nPer) {
        const unsigned short* Ach = latb16 + (size_t)nb * 8 * 512;
        k_mfma_gemm<0, 1><<<dim3(250, chunkRows / 128), 256, 0, stream>>>(
            Ach, decWb, decb, logits, chunkRows, 32000, 512, nullptr);
        k_stats<<<chunkRows, 256, 0, stream>>>(logits, stats);
        k_combine<<<dim3(125, nPer), 256, 0, stream>>>(
            logits, stats, pri, (float*)d_out, nb);
    }
}

// Round 3
// 3197.932 us; speedup vs baseline: 3.3001x; 3.3001x over previous
//
#include <hip/hip_runtime.h>
#include <hip/hip_bf16.h>

typedef __attribute__((ext_vector_type(8))) short short8;
typedef __attribute__((ext_vector_type(4))) float f32x4;
typedef unsigned short u16;

__device__ __forceinline__ u16 f2b(float f) {
    unsigned u = __float_as_uint(f);
    return (u16)((u + 0x7FFFu + ((u >> 16) & 1u)) >> 16);
}
__device__ __forceinline__ float b2f(u16 u) {
    return __uint_as_float(((unsigned)u) << 16);
}
__device__ __forceinline__ void gload16(const void* g, void* l) {
    __builtin_amdgcn_global_load_lds(
        (const __attribute__((address_space(1))) void*)g,
        (__attribute__((address_space(3))) void*)l, 16, 0, 0);
}

// ---------------------------------------------------------------------------
// f32 -> bf16 bulk convert
// ---------------------------------------------------------------------------
__global__ __launch_bounds__(256)
void k_f2b(const float* __restrict__ s, u16* __restrict__ d, int n4)
{
    int i = blockIdx.x * 256 + threadIdx.x;
    if (i >= n4) return;
    float4 v = ((const float4*)s)[i];
    short4 o;
    o.x = (short)f2b(v.x); o.y = (short)f2b(v.y);
    o.z = (short)f2b(v.z); o.w = (short)f2b(v.w);
    ((short4*)d)[i] = o;
}

// ---------------------------------------------------------------------------
// Embedding gather -> bf16: x0[n][p] = bf16(emb[tok[n]][p])
// ---------------------------------------------------------------------------
__global__ __launch_bounds__(256)
void k_embed(const int* __restrict__ tok, const float* __restrict__ emb,
             u16* __restrict__ x0)
{
    int i = blockIdx.x * 256 + threadIdx.x;   // 131072: 4 elems each
    int n = i >> 7, p4 = i & 127;
    float4 v = ((const float4*)(emb + (size_t)tok[n] * 512))[p4];
    short4 o;
    o.x = (short)f2b(v.x); o.y = (short)f2b(v.y);
    o.z = (short)f2b(v.z); o.w = (short)f2b(v.w);
    ((short4*)x0)[i] = o;
}

// ---------------------------------------------------------------------------
// State init: h (bf16) <- h0 (f32); c (f32) <- c0
// ---------------------------------------------------------------------------
__global__ __launch_bounds__(256)
void k_state_init(const float* __restrict__ h0, const float* __restrict__ c0,
                  u16* __restrict__ h, float* __restrict__ c, int n)
{
    int i = blockIdx.x * 256 + threadIdx.x;
    if (i < n) { h[i] = f2b(h0[i]); c[i] = c0[i]; }
}

// ---------------------------------------------------------------------------
// MFMA bf16 GEMM (m97-style): C[M,N] = A[M,K](bf16) * B[N,K]^T + bias
// Block 128x128, 4 waves (2x2), wave tile 64x64, K-step 32, linear LDS,
// A staged via global_load_lds (width 16).
// BIN=1: B bf16, staged via global_load_lds. BIN=0: B f32, reg-convert stage.
// EPI=0: C f32 row-major. EPI=1: latent head -> bf16, remap (e,p), tanh*gain.
// M%128==0, N%128==0, K%32==0.
// ---------------------------------------------------------------------------
template <int EPI, int BIN>
__global__ __launch_bounds__(256)
void k_gemm(const u16* __restrict__ A, const void* __restrict__ Bp,
            const float* __restrict__ bias, void* __restrict__ Cp,
            int M, int N, int K, const float* __restrict__ gain)
{
    __shared__ __align__(16) u16 As[128 * 32];
    __shared__ __align__(16) u16 Bs[128 * 32];
    const int tid = threadIdx.x;
    const int lane = tid & 63, wid = tid >> 6;
    const int wr = wid >> 1, wc = wid & 1;
    const int l15 = lane & 15, l4 = lane >> 4;
    const int row0 = blockIdx.y * 128, col0 = blockIdx.x * 128;

    // global_load_lds staging geometry: slot q in {0,1}; wave w covers LDS
    // rows (q*4+w)*16 + lane/4, k-offset (lane&3)*8
    const int srA = wid * 16 + (lane >> 2);
    const int skA = (lane & 3) * 8;
    // f32 B staging geometry (BIN==0)
    const int srow = tid >> 1, skh = (tid & 1) << 4;

    f32x4 acc[4][4] = {};

    for (int k0 = 0; k0 < K; k0 += 32) {
        if (k0) __syncthreads();
        // stage A (8KB) via 2 global_load_lds slots
        gload16(A + (size_t)(row0 + srA) * K + k0 + skA, As + wid * 512);
        gload16(A + (size_t)(row0 + 64 + srA) * K + k0 + skA, As + 2048 + wid * 512);
        if (BIN == 1) {
            const u16* B = (const u16*)Bp;
            gload16(B + (size_t)(col0 + srA) * K + k0 + skA, Bs + wid * 512);
            gload16(B + (size_t)(col0 + 64 + srA) * K + k0 + skA, Bs + 2048 + wid * 512);
        } else {
            const float* B = (const float*)Bp;
            const float4* sb = (const float4*)(B + (size_t)(col0 + srow) * K + k0 + skh);
            float tmp[16];
            *(float4*)&tmp[0]  = sb[0];
            *(float4*)&tmp[4]  = sb[1];
            *(float4*)&tmp[8]  = sb[2];
            *(float4*)&tmp[12] = sb[3];
            short8 v0, v1;
#pragma unroll
            for (int i = 0; i < 8; ++i) { v0[i] = (short)f2b(tmp[i]); v1[i] = (short)f2b(tmp[8 + i]); }
            *(short8*)&Bs[srow * 32 + skh]     = v0;
            *(short8*)&Bs[srow * 32 + skh + 8] = v1;
        }
        __syncthreads();

        short8 af[4], bfv[4];
#pragma unroll
        for (int i = 0; i < 4; ++i)
            af[i]  = *(const short8*)&As[(wr * 64 + i * 16 + l15) * 32 + l4 * 8];
#pragma unroll
        for (int i = 0; i < 4; ++i)
            bfv[i] = *(const short8*)&Bs[(wc * 64 + i * 16 + l15) * 32 + l4 * 8];
#pragma unroll
        for (int mi = 0; mi < 4; ++mi)
#pragma unroll
            for (int ni = 0; ni < 4; ++ni)
                acc[mi][ni] = __builtin_amdgcn_mfma_f32_16x16x32_bf16(
                    af[mi], bfv[ni], acc[mi][ni], 0, 0, 0);
    }

#pragma unroll
    for (int mi = 0; mi < 4; ++mi) {
#pragma unroll
        for (int ni = 0; ni < 4; ++ni) {
            int rb = row0 + wr * 64 + mi * 16 + l4 * 4;
            int cc = col0 + wc * 64 + ni * 16 + l15;
            float bv = bias[cc];
#pragma unroll
            for (int j = 0; j < 4; ++j) {
                float v = acc[mi][ni][j] + bv;
                if (EPI == 0) {
                    ((float*)Cp)[(size_t)(rb + j) * N + cc] = v;
                } else {
                    int e = cc >> 9, pp = cc & 511;
                    ((u16*)Cp)[(((size_t)(rb + j) * 8 + e) << 9) | pp] =
                        f2b(tanhf(v) * gain[pp]);
                }
            }
        }
    }
}

// ---------------------------------------------------------------------------
// One LSTM step via MFMA. Block = 256 thr = 4 waves, one 16-unit tile,
// all 4 gates; wave w accumulates K-quarter w. Grid = DH/16.
// A = h_prev (16 x DH bf16), B = Whh (4DH x DH bf16), frags straight from
// global (fragment layout == row-major slices). LDS cross-wave reduce,
// fused sigmoid/tanh gate math, writes h (bf16), y (bf16), c (f32).
// ---------------------------------------------------------------------------
template <int DH>
__global__ __launch_bounds__(256)
void k_lstm_step(const float* __restrict__ xg,      // (1024, 4*DH) f32
                 const u16* __restrict__ W,         // (4*DH, DH) bf16
                 const u16* __restrict__ h_in,      // (16, DH) bf16
                 u16* __restrict__ h_out,           // (16, DH) bf16
                 float* __restrict__ c,             // (16, DH) f32 in/out
                 u16* __restrict__ y,               // (1024, DH) bf16
                 int t)
{
    constexpr int KQ = DH / 4;
    constexpr int NSTEP = KQ / 32;
    __shared__ __align__(16) f32x4 red[4][4][64];   // [wave][gate][lane]
    const int tid = threadIdx.x;
    const int lane = tid & 63, wid = tid >> 6;
    const int l15 = lane & 15, l4 = lane >> 4;
    const int u0 = blockIdx.x * 16;
    const int kb = wid * KQ;

    f32x4 acc[4] = {};
    const u16* ha = h_in + (size_t)l15 * DH + kb + l4 * 8;
    const u16* wa = W + (size_t)(u0 + l15) * DH + kb + l4 * 8;
#pragma unroll
    for (int s = 0; s < NSTEP; ++s) {
        short8 hf = *(const short8*)(ha + s * 32);
#pragma unroll
        for (int g = 0; g < 4; ++g) {
            short8 wf = *(const short8*)(wa + (size_t)g * DH * DH + s * 32);
            acc[g] = __builtin_amdgcn_mfma_f32_16x16x32_bf16(hf, wf, acc[g], 0, 0, 0);
        }
    }
#pragma unroll
    for (int g = 0; g < 4; ++g) red[wid][g][lane] = acc[g];
    __syncthreads();

    // epilogue: thread -> (b, ul)
    const int b = tid >> 4, ul = tid & 15;
    const int li = (b >> 2) * 16 + ul, j = b & 3;
    float gate[4];
#pragma unroll
    for (int g = 0; g < 4; ++g) {
        const float* p0 = (const float*)&red[0][g][li];
        const float* p1 = (const float*)&red[1][g][li];
        const float* p2 = (const float*)&red[2][g][li];
        const float* p3 = (const float*)&red[3][g][li];
        gate[g] = p0[j] + p1[j] + p2[j] + p3[j];
    }

    const int n = t * 16 + b;
    const int u = u0 + ul;
    const float* xr = xg + (size_t)n * 4 * DH;
    float gi = xr[u]          + gate[0];
    float gf = xr[DH + u]     + gate[1];
    float gg = xr[2 * DH + u] + gate[2];
    float go = xr[3 * DH + u] + gate[3];
    float si = 1.f / (1.f + expf(-gi));
    float sf = 1.f / (1.f + expf(-gf));
    float so = 1.f / (1.f + expf(-go));
    const int ci = b * DH + u;
    float cn = sf * c[ci] + si * tanhf(gg);
    c[ci] = cn;
    float hn = so * tanhf(cn);
    u16 hb = f2b(hn);
    h_out[ci] = hb;
    y[(size_t)n * DH + u] = hb;
}

// ---------------------------------------------------------------------------
// Prior: softmax over 8 experts of out2(1024x1024 bf16) @ prior_W^T(8x1024 f32)
// ---------------------------------------------------------------------------
__global__ __launch_bounds__(256)
void k_prior(const u16* __restrict__ out2, const float* __restrict__ pW,
             float* __restrict__ prior)
{
    const int n = blockIdx.x;
    const int tid = threadIdx.x;
    const int e = tid >> 5, lane = tid & 31;
    const u16* x = out2 + (size_t)n * 1024;
    const float* w = pW + (size_t)e * 1024;
    float s = 0.f;
    for (int k = lane; k < 1024; k += 32) s += b2f(x[k]) * w[k];
#pragma unroll
    for (int o = 16; o; o >>= 1) s += __shfl_down(s, o, 32);
    __shared__ float es[8];
    if (lane == 0) es[e] = s;
    __syncthreads();
    if (tid == 0) {
        float m = -1e30f;
        for (int i = 0; i < 8; ++i) m = fmaxf(m, es[i]);
        float Z = 0.f, ex[8];
        for (int i = 0; i < 8; ++i) { ex[i] = expf(es[i] - m); Z += ex[i]; }
        for (int i = 0; i < 8; ++i) prior[(size_t)n * 8 + i] = ex[i] / Z;
    }
}

// ---------------------------------------------------------------------------
// Row stats: per-row max and sum(exp(x-max)) over 32000 cols (f32, float4).
// ---------------------------------------------------------------------------
__global__ __launch_bounds__(256)
void k_stats(const float* __restrict__ lg, float* __restrict__ stats)
{
    const int r = blockIdx.x;
    const float4* row = (const float4*)(lg + (size_t)r * 32000);
    const int tid = threadIdx.x;

    float m = -1e30f;
    for (int k = tid; k < 8000; k += 256) {
        float4 v = row[k];
        m = fmaxf(m, fmaxf(fmaxf(v.x, v.y), fmaxf(v.z, v.w)));
    }
#pragma unroll
    for (int o = 32; o; o >>= 1) m = fmaxf(m, __shfl_down(m, o, 64));
    __shared__ float sm[4];
    if ((tid & 63) == 0) sm[tid >> 6] = m;
    __syncthreads();
    float M = fmaxf(fmaxf(sm[0], sm[1]), fmaxf(sm[2], sm[3]));

    float s = 0.f;
    for (int k = tid; k < 8000; k += 256) {
        float4 v = row[k];
        s += expf(v.x - M) + expf(v.y - M) + expf(v.z - M) + expf(v.w - M);
    }
#pragma unroll
    for (int o = 32; o; o >>= 1) s += __shfl_down(s, o, 64);
    __shared__ float ss[4];
    if ((tid & 63) == 0) ss[tid >> 6] = s;
    __syncthreads();
    if (tid == 0) {
        stats[2 * r]     = M;
        stats[2 * r + 1] = ss[0] + ss[1] + ss[2] + ss[3];
    }
}

// ---------------------------------------------------------------------------
// Combine: out[n][v] = log( sum_e prior[n,e]*exp(l[ne,v]-M_e)/Z_e + 1e-8 )
// ---------------------------------------------------------------------------
__global__ __launch_bounds__(256)
void k_combine(const float* __restrict__ lg, const float* __restrict__ stats,
               const float* __restrict__ prior, float* __restrict__ out, int n0)
{
    const int v = blockIdx.x * 256 + threadIdx.x;
    const int nl = blockIdx.y;
    const int n = n0 + nl;
    float acc = 0.f;
#pragma unroll
    for (int e = 0; e < 8; ++e) {
        int r = nl * 8 + e;
        float l = lg[(size_t)r * 32000 + v];
        acc += prior[(size_t)n * 8 + e] * expf(l - stats[2 * r]) / stats[2 * r + 1];
    }
    out[(size_t)n * 32000 + v] = logf(acc + 1e-8f);
}

// ---------------------------------------------------------------------------
extern "C" void kernel_launch(void* const* d_in, const int* in_sizes, int n_in,
                              void* d_out, int out_size, void* d_ws, size_t ws_size,
                              hipStream_t stream)
{
    const int*   tok  = (const int*)d_in[0];
    const float* h0   = (const float*)d_in[1];
    const float* c0   = (const float*)d_in[2];
    const float* h1   = (const float*)d_in[3];
    const float* c1   = (const float*)d_in[4];
    const float* h2   = (const float*)d_in[5];
    const float* c2   = (const float*)d_in[6];
    const float* emb  = (const float*)d_in[7];
    const float* Wih0 = (const float*)d_in[8];
    const float* Whh0 = (const float*)d_in[9];
    const float* b0   = (const float*)d_in[10];
    const float* Wih1 = (const float*)d_in[11];
    const float* Whh1 = (const float*)d_in[12];
    const float* b1   = (const float*)d_in[13];
    const float* Wih2 = (const float*)d_in[14];
    const float* Whh2 = (const float*)d_in[15];
    const float* b2   = (const float*)d_in[16];
    const float* priW = (const float*)d_in[17];
    const float* latW = (const float*)d_in[18];
    const float* latb = (const float*)d_in[19];
    const float* decW = (const float*)d_in[20];
    const float* decb = (const float*)d_in[21];
    const float* gain = (const float*)d_in[22];

    // bump allocator (256B aligned)
    char* p = (char*)d_ws;
    auto alloc = [&](size_t bytes) {
        char* r = p; p += (bytes + 255) & ~(size_t)255; return r;
    };
    u16* Whh0b = (u16*)alloc(6144ull * 1536 * 2);
    u16* Whh1b = (u16*)alloc(6144ull * 1536 * 2);
    u16* Whh2b = (u16*)alloc(4096ull * 1024 * 2);
    u16* latWb = (u16*)alloc(4096ull * 1024 * 2);
    u16* decWb = (u16*)alloc(32000ull * 512 * 2);
    u16* latb16 = (u16*)alloc(8192ull * 512 * 2);
    float* pri   = (float*)alloc(8192 * 4);
    float* stats = (float*)alloc(1024 * 4);
    u16* hA = (u16*)alloc(16 * 1536 * 2);
    u16* hB = (u16*)alloc(16 * 1536 * 2);
    float* cb = (float*)alloc(16 * 1536 * 4);
    u16* out2 = (u16*)alloc(1024ull * 1024 * 2);
    char* trans = p;                      // transient region; logits aliases it
    u16* x0 = (u16*)alloc(1024ull * 512 * 2);
    u16* x1 = (u16*)alloc(1024ull * 1536 * 2);
    u16* x2 = (u16*)alloc(1024ull * 1536 * 2);
    float* xg = (float*)alloc(1024ull * 6144 * 4);
    float* logits = (float*)trans;
    size_t cap = ws_size - (size_t)(trans - (char*)d_ws);
    int chunkRows = 128;
    if (cap >= 512ull * 32000 * 4) chunkRows = 512;
    else if (cap >= 256ull * 32000 * 4) chunkRows = 256;
    int nPer = chunkRows / 8;

    // weight conversions + embedding
    k_f2b<<<9216, 256, 0, stream>>>(Whh0, Whh0b, 2359296);
    k_f2b<<<9216, 256, 0, stream>>>(Whh1, Whh1b, 2359296);
    k_f2b<<<4096, 256, 0, stream>>>(Whh2, Whh2b, 1048576);
    k_f2b<<<4096, 256, 0, stream>>>(latW, latWb, 1048576);
    k_f2b<<<16000, 256, 0, stream>>>(decW, decWb, 4096000);
    k_embed<<<512, 256, 0, stream>>>(tok, emb, x0);

    // ---- layer 0 (512 -> 1536) ----
    k_state_init<<<96, 256, 0, stream>>>(h0, c0, hA, cb, 16 * 1536);
    k_gemm<0, 0><<<dim3(48, 8), 256, 0, stream>>>(
        x0, Wih0, b0, xg, 1024, 6144, 512, nullptr);
    for (int t = 0; t < 64; ++t) {
        const u16* hin = (t & 1) ? hB : hA;
        u16* hout = (t & 1) ? hA : hB;
        k_lstm_step<1536><<<96, 256, 0, stream>>>(xg, Whh0b, hin, hout, cb, x1, t);
    }

    // ---- layer 1 (1536 -> 1536) ----
    k_state_init<<<96, 256, 0, stream>>>(h1, c1, hA, cb, 16 * 1536);
    k_gemm<0, 0><<<dim3(48, 8), 256, 0, stream>>>(
        x1, Wih1, b1, xg, 1024, 6144, 1536, nullptr);
    for (int t = 0; t < 64; ++t) {
        const u16* hin = (t & 1) ? hB : hA;
        u16* hout = (t & 1) ? hA : hB;
        k_lstm_step<1536><<<96, 256, 0, stream>>>(xg, Whh1b, hin, hout, cb, x2, t);
    }

    // ---- layer 2 (1536 -> 1024) ----
    k_state_init<<<64, 256, 0, stream>>>(h2, c2, hA, cb, 16 * 1024);
    k_gemm<0, 0><<<dim3(32, 8), 256, 0, stream>>>(
        x2, Wih2, b2, xg, 1024, 4096, 1536, nullptr);
    for (int t = 0; t < 64; ++t) {
        const u16* hin = (t & 1) ? hB : hA;
        u16* hout = (t & 1) ? hA : hB;
        k_lstm_step<1024><<<64, 256, 0, stream>>>(xg, Whh2b, hin, hout, cb, out2, t);
    }

    // ---- MoS head ----
    k_prior<<<1024, 256, 0, stream>>>(out2, priW, pri);
    k_gemm<1, 1><<<dim3(32, 8), 256, 0, stream>>>(
        out2, latWb, latb, latb16, 1024, 4096, 1024, gain);

    // ---- decoder, chunked (logits aliases dead transient region) ----
    for (int nb = 0; nb < 1024; nb += nPer) {
        const u16* Ach = latb16 + (size_t)nb * 8 * 512;
        k_gemm<0, 1><<<dim3(250, chunkRows / 128), 256, 0, stream>>>(
            Ach, decWb, decb, logits, chunkRows, 32000, 512, nullptr);
        k_stats<<<chunkRows, 256, 0, stream>>>(logits, stats);
        k_combine<<<dim3(125, nPer), 256, 0, stream>>>(
            logits, stats, pri, (float*)d_out, nb);
    }
}